// Round 14
// baseline (183.310 us; speedup 1.0000x reference)
//
#include <hip/hip_runtime.h>
#include <hip/hip_bf16.h>
#include <stdint.h>

typedef __bf16 bf16x8 __attribute__((ext_vector_type(8)));
typedef float f32x4 __attribute__((ext_vector_type(4)));
typedef float f32x16 __attribute__((ext_vector_type(16)));
typedef unsigned short ushort8v __attribute__((ext_vector_type(8)));
typedef unsigned short ushort4v __attribute__((ext_vector_type(4)));
typedef uint32_t uint2v __attribute__((ext_vector_type(2)));
typedef uint32_t uint4v __attribute__((ext_vector_type(4)));

#define MFMA16(a, b, c) __builtin_amdgcn_mfma_f32_16x16x32_bf16(a, b, c, 0, 0, 0)
#define MFMA32(a, b, c) __builtin_amdgcn_mfma_f32_32x32x16_bf16(a, b, c, 0, 0, 0)

// async global->LDS, 16B per lane; LDS dest = wave-uniform base + lane*16
#define GLOAD_LDS16(g, l)                                                        \
    __builtin_amdgcn_global_load_lds(                                            \
        (const __attribute__((address_space(1))) uint32_t*)(g),                  \
        (__attribute__((address_space(3))) uint32_t*)(l), 16, 0, 0)

#define QSCALE 0.1803368801f  // 0.125 * log2(e)

__device__ __forceinline__ unsigned short f2bf_u(float f) {
    union { float f; uint32_t u; } cv; cv.f = f;
    uint32_t u = cv.u;
    uint32_t r = (u + 0x7FFFu + ((u >> 16) & 1u)) >> 16;
    return (unsigned short)r;
}

__device__ __forceinline__ float bf2f(unsigned short u) {
    union { uint32_t u; float f; } cv;
    cv.u = (uint32_t)u << 16;
    return cv.f;
}

__device__ __forceinline__ uint32_t pkbf(float a, float b) {
    union { __hip_bfloat162 h; uint32_t u; } cv;
    cv.h = __float22bfloat162_rn(make_float2(a, b));
    return cv.u;
}

__device__ __forceinline__ float fexp2(float x) { return __builtin_amdgcn_exp2f(x); }

// ---------------------------------------------------------------------------
// Transpose + cast v2: Wt[n][k] = bf16(W[k][n]); z selects Wq/Wk/Wv.
// 64x64 tiles, float4 loads, ushort4 stores; 65-float LDS stride (2-way max).
// ---------------------------------------------------------------------------
__global__ __launch_bounds__(256) void wt_cast(const float* __restrict__ W0,
                                               const float* __restrict__ W1,
                                               const float* __restrict__ W2,
                                               unsigned short* __restrict__ T0,
                                               unsigned short* __restrict__ T1,
                                               unsigned short* __restrict__ T2) {
    const int z = blockIdx.z;
    const float* W = z == 0 ? W0 : (z == 1 ? W1 : W2);
    unsigned short* Wt = z == 0 ? T0 : (z == 1 ? T1 : T2);
    __shared__ float t[64][65];
    const int tx = threadIdx.x & 15, ty = threadIdx.x >> 4;  // 16 x 16
    const int n0 = blockIdx.x * 64, k0 = blockIdx.y * 64;
#pragma unroll
    for (int i = 0; i < 4; i++) {
        const int r = i * 16 + ty;
        *reinterpret_cast<float4*>(&t[r][tx * 4]) =
            *reinterpret_cast<const float4*>(&W[(size_t)(k0 + r) * 1024 + n0 + tx * 4]);
    }
    __syncthreads();
#pragma unroll
    for (int i = 0; i < 4; i++) {
        const int n = i * 16 + ty;
        ushort4v v;
#pragma unroll
        for (int j = 0; j < 4; j++) v[j] = f2bf_u(t[tx * 4 + j][n]);
        *reinterpret_cast<ushort4v*>(&Wt[(size_t)(n0 + n) * 1024 + k0 + tx * 4]) = v;
    }
}

// ---------------------------------------------------------------------------
// QKV GEMM v4: out = relu(A_fp32 @ W + bias), A converted to bf16 in-kernel.
// W staged via global_load_lds (DMA); A reg-staged with the load/write SPLIT
// across K-iterations (LOAD_A(col k+2) at iter k, WRITE_A at iter k+1).
// BK=32 double-buffered, one barrier per K-step. 1-D grid 1536, XCD remap.
// z==0 (Q): epilogue folds attention scale + query mask: q *= mask? QSCALE : 0.
// z==2 (V): writes transposed [B,H,dh,S].
// ---------------------------------------------------------------------------
__global__ __launch_bounds__(256) void qkv_gemm4(
    const float* __restrict__ Aq, const float* __restrict__ Ak,
    const float* __restrict__ Av,
    const unsigned short* __restrict__ Wq, const unsigned short* __restrict__ Wk,
    const unsigned short* __restrict__ Wv,
    const float* __restrict__ biasq, const float* __restrict__ biask,
    const float* __restrict__ biasv, const int* __restrict__ mask,
    unsigned short* __restrict__ outq, unsigned short* __restrict__ outk,
    unsigned short* __restrict__ outv) {
    __shared__ __align__(16) unsigned short aS[2][128 * 32];
    __shared__ __align__(16) unsigned short wS[2][128 * 32];
    const int id = blockIdx.x;          // 0..1535
    const int xcd = id & 7;
    const int local = id >> 3;          // 0..191
    const int z = local >> 6;           // 0..2
    const int l2i = local & 63;         // 0..63
    const int m0 = (xcd * 8 + (l2i >> 3)) * 128;
    const int n0 = (l2i & 7) * 128;

    const float* A = z == 0 ? Aq : (z == 1 ? Ak : Av);
    const unsigned short* Wt = z == 0 ? Wq : (z == 1 ? Wk : Wv);
    const float* bias = z == 0 ? biasq : (z == 1 ? biask : biasv);
    unsigned short* out = z == 0 ? outq : (z == 1 ? outk : outv);
    const bool vt = (z == 2);

    const int tid = threadIdx.x;
    const int lane = tid & 63, wave = tid >> 6;
    const int rrow = lane & 15, rgrp = lane >> 4;
    const int wm = wave >> 1, wn = wave & 1;

    const int row0 = tid >> 2, c0 = tid & 3;
    const int row1 = (tid + 256) >> 2;
    const int arow_f = wm * 64 + rrow;                   // + mi*16
    const int brow_f = wn * 64 + rrow;                   // + ni*16

    f32x4 acc[4][4];
#pragma unroll
    for (int i = 0; i < 4; i++)
#pragma unroll
        for (int j = 0; j < 4; j++) acc[i][j] = (f32x4)0.0f;

    auto STAGE_W = [&](int k0, int bufi) {
        char* dst = (char*)&wS[bufi][0] + wave * 1024;   // + implicit lane*16
        GLOAD_LDS16((const char*)Wt + ((size_t)(n0 + row0) * 1024 + k0 + c0 * 8) * 2, dst);
        GLOAD_LDS16((const char*)Wt + ((size_t)(n0 + row1) * 1024 + k0 + c0 * 8) * 2,
                    dst + 4096);
    };
    auto LOAD_A = [&](int k0, float4* r) {
#pragma unroll
        for (int i = 0; i < 4; i++) {
            const int g = i * 256 + tid, row = g >> 3, qc = g & 7;
            r[i] = *reinterpret_cast<const float4*>(A + (size_t)(m0 + row) * 1024 + k0 + qc * 4);
        }
    };
    auto WRITE_A = [&](const float4* r, int bufi) {
#pragma unroll
        for (int i = 0; i < 4; i++) {
            const int g = i * 256 + tid, row = g >> 3, qc = g & 7;
            uint2v w;
            w[0] = pkbf(r[i].x, r[i].y);
            w[1] = pkbf(r[i].z, r[i].w);
            *reinterpret_cast<uint2v*>((char*)&aS[bufi][0] + row * 64 + qc * 8) = w;
        }
    };

    float4 aload[4];
    LOAD_A(0, aload);
    STAGE_W(0, 0);
    WRITE_A(aload, 0);
    LOAD_A(32, aload);
    __syncthreads();

    for (int ks = 0; ks < 32; ks++) {
        const int cur = ks & 1;
        if (ks < 31) {
            WRITE_A(aload, cur ^ 1);            // data for col ks+1 (loaded iter ks-1)
            STAGE_W((ks + 1) * 32, cur ^ 1);
            if (ks < 30) LOAD_A((ks + 2) * 32, aload);
        }

        bf16x8 af[4], bfr[4];
#pragma unroll
        for (int mi = 0; mi < 4; mi++)
            af[mi] = *reinterpret_cast<const bf16x8*>(
                (const char*)&aS[cur][0] + (arow_f + mi * 16) * 64 + rgrp * 16);
#pragma unroll
        for (int ni = 0; ni < 4; ni++)
            bfr[ni] = *reinterpret_cast<const bf16x8*>(
                (const char*)&wS[cur][0] + (brow_f + ni * 16) * 64 + rgrp * 16);
        __builtin_amdgcn_s_setprio(1);
#pragma unroll
        for (int mi = 0; mi < 4; mi++)
#pragma unroll
            for (int ni = 0; ni < 4; ni++)
                acc[mi][ni] = MFMA16(af[mi], bfr[ni], acc[mi][ni]);
        __builtin_amdgcn_s_setprio(0);

        __syncthreads();
    }

    // Epilogue: bias + relu (+ Q scale*mask) + bf16, scatter head-split.
#pragma unroll
    for (int mi = 0; mi < 4; mi++) {
        const int mbase = m0 + wm * 64 + mi * 16 + rgrp * 4;
        const int b = mbase >> 11, s = mbase & 2047;
        float qs[4];
#pragma unroll
        for (int jr = 0; jr < 4; jr++)
            qs[jr] = (z != 0) ? 1.0f : (mask[b * 2048 + s + jr] ? QSCALE : 0.0f);
#pragma unroll
        for (int ni = 0; ni < 4; ni++) {
            const int n = n0 + wn * 64 + ni * 16 + rrow;
            const float bv = bias[n];
            const int h = n >> 6, d = n & 63;
            if (vt) {
                ushort4v pv;
#pragma unroll
                for (int jr = 0; jr < 4; jr++)
                    pv[jr] = f2bf_u(fmaxf(acc[mi][ni][jr] + bv, 0.0f));
                *reinterpret_cast<ushort4v*>(out + ((size_t)((b * 16 + h) * 64 + d)) * 2048 + s) = pv;
            } else {
#pragma unroll
                for (int jr = 0; jr < 4; jr++)
                    out[((size_t)((b * 16 + h) * 2048 + (s + jr))) * 64 + d] =
                        f2bf_u(fmaxf(acc[mi][ni][jr] + bv, 0.0f) * qs[jr]);
            }
        }
    }
}

// ---------------------------------------------------------------------------
// Flash attention. 4 waves/block share one (b,h); K/V tiles staged to LDS via
// global_load_lds (double-buffered 2-phase). Swapped-QK^T 32x32. Q pre-scaled
// by mask*0.125*log2e, so P = 2^S with fixed m=0 (scores bounded); masked
// rows Q=0 -> P=1 uniform (= reference). P->A-fragment pack via
// v_permlane32_swap_b32. l via MFMA (P . ones); O written bf16.
// ---------------------------------------------------------------------------
__global__ __launch_bounds__(256, 4) void flash_attn(const unsigned short* __restrict__ Qg,
                                                     const unsigned short* __restrict__ Kg,
                                                     const unsigned short* __restrict__ Vt,
                                                     unsigned short* __restrict__ O) {
    __shared__ __align__(16) unsigned short ldsK[2][64 * 64];  // 8KB per buffer
    __shared__ __align__(16) unsigned short ldsV[2][64 * 64];
    const int tid = threadIdx.x;
    const int lane = tid & 63, wave = tid >> 6;
    const int c = lane & 31, hi = lane >> 5;
    const int bid = blockIdx.x;                      // 1024 blocks
    const int swzb = (bid & 7) * 128 + (bid >> 3);   // XCD-contiguous block id
    const int gid = swzb * 4 + wave;                 // wave id in [0,4096)
    const int bh = gid >> 6;                         // all 4 waves: same bh
    const int q0 = (gid & 63) * 32;
    const int b = bh >> 4, h = bh & 15;
    const size_t base = (size_t)bh * (2048 * 64);
    const unsigned short* Qb = Qg + base;
    const unsigned short* Kb = Kg + base;
    const unsigned short* Vb = Vt + base;  // [64][2048]

    // staging constants: lane covers 16B chunk (lane&7) of row stripe (lane>>3)
    const int srow = lane >> 3;                 // 0..7
    const int schunk = (lane & 7) ^ srow;       // inverse-swizzled source chunk
    int offL[4], offH[4];
#pragma unroll
    for (int ds = 0; ds < 4; ds++) {
        offL[ds] = c * 128 + ((((ds << 1) + hi) ^ (c & 7)) << 4);
        offH[ds] = offL[ds] + 32 * 128;
    }

    bf16x8 qf[4];
#pragma unroll
    for (int ds = 0; ds < 4; ds++)
        qf[ds] = *reinterpret_cast<const bf16x8*>(Qb + (size_t)(q0 + c) * 64 + ds * 16 + hi * 8);

    union { uint32_t u[4]; bf16x8 v; } onesf;
#pragma unroll
    for (int i = 0; i < 4; i++) onesf.u[i] = 0x3F803F80u;  // bf16 1.0 x8

    f32x16 lacc = (f32x16)0.0f;
    f32x16 oacc0 = (f32x16)0.0f, oacc1 = (f32x16)0.0f;

    auto STAGE = [&](int kt, int bufi) {
        const char* ktile = (const char*)Kb + (size_t)kt * 8192;      // contiguous
        const char* vtile = (const char*)Vb + (size_t)kt * 128;       // strided rows
        char* kdst = (char*)&ldsK[bufi][0] + wave * 2048;
        char* vdst = (char*)&ldsV[bufi][0] + wave * 2048;
#pragma unroll
        for (int i = 0; i < 2; i++) {
            const int row = wave * 16 + i * 8 + srow;
            GLOAD_LDS16(ktile + row * 128 + schunk * 16, kdst + i * 1024);
            GLOAD_LDS16(vtile + (size_t)row * 4096 + schunk * 16, vdst + i * 1024);
        }
    };

    STAGE(0, 0);
    __syncthreads();

    for (int kt = 0; kt < 32; kt++) {
        const int cur = kt & 1;
        if (kt < 31) STAGE(kt + 1, cur ^ 1);
        const char* kbuf = (const char*)&ldsK[cur][0];
        const char* vbuf = (const char*)&ldsV[cur][0];

        // ---- S^T = K Q^T (Q pre-scaled; base-2 domain) ----
        f32x16 sacc0 = (f32x16)0.0f, sacc1 = (f32x16)0.0f;
        __builtin_amdgcn_s_setprio(1);
#pragma unroll
        for (int ds = 0; ds < 4; ds++) {
            bf16x8 k0 = *reinterpret_cast<const bf16x8*>(kbuf + offL[ds]);
            bf16x8 k1 = *reinterpret_cast<const bf16x8*>(kbuf + offH[ds]);
            sacc0 = MFMA32(k0, qf[ds], sacc0);
            sacc1 = MFMA32(k1, qf[ds], sacc1);
        }
        __builtin_amdgcn_s_setprio(0);

        // ---- P = 2^S in place ----
#pragma unroll
        for (int j = 0; j < 16; j++) {
            sacc0[j] = fexp2(sacc0[j]);
            sacc1[j] = fexp2(sacc1[j]);
        }

        // ---- half 0: pack P(keys 0..31) via permlane32_swap, l, O += P V ----
        {
            uint32_t w0[8];
#pragma unroll
            for (int i = 0; i < 8; i++) w0[i] = pkbf(sacc0[2 * i], sacc0[2 * i + 1]);
            asm("v_permlane32_swap_b32 %0, %1" : "+v"(w0[0]), "+v"(w0[2]));
            asm("v_permlane32_swap_b32 %0, %1" : "+v"(w0[1]), "+v"(w0[3]));
            asm("v_permlane32_swap_b32 %0, %1" : "+v"(w0[4]), "+v"(w0[6]));
            asm("v_permlane32_swap_b32 %0, %1" : "+v"(w0[5]), "+v"(w0[7]));
            union { uint32_t u[4]; bf16x8 v; } pa[2];
            pa[0].u[0] = w0[0]; pa[0].u[1] = w0[1]; pa[0].u[2] = w0[2]; pa[0].u[3] = w0[3];
            pa[1].u[0] = w0[4]; pa[1].u[1] = w0[5]; pa[1].u[2] = w0[6]; pa[1].u[3] = w0[7];
            __builtin_amdgcn_s_setprio(1);
#pragma unroll
            for (int ks = 0; ks < 2; ks++) {
                bf16x8 v0 = *reinterpret_cast<const bf16x8*>(vbuf + offL[ks]);
                bf16x8 v1 = *reinterpret_cast<const bf16x8*>(vbuf + offH[ks]);
                lacc = MFMA32(pa[ks].v, onesf.v, lacc);
                oacc0 = MFMA32(pa[ks].v, v0, oacc0);
                oacc1 = MFMA32(pa[ks].v, v1, oacc1);
            }
            __builtin_amdgcn_s_setprio(0);
        }
        // ---- half 1: keys 32..63 ----
        {
            uint32_t w1[8];
#pragma unroll
            for (int i = 0; i < 8; i++) w1[i] = pkbf(sacc1[2 * i], sacc1[2 * i + 1]);
            asm("v_permlane32_swap_b32 %0, %1" : "+v"(w1[0]), "+v"(w1[2]));
            asm("v_permlane32_swap_b32 %0, %1" : "+v"(w1[1]), "+v"(w1[3]));
            asm("v_permlane32_swap_b32 %0, %1" : "+v"(w1[4]), "+v"(w1[6]));
            asm("v_permlane32_swap_b32 %0, %1" : "+v"(w1[5]), "+v"(w1[7]));
            union { uint32_t u[4]; bf16x8 v; } pa[2];
            pa[0].u[0] = w1[0]; pa[0].u[1] = w1[1]; pa[0].u[2] = w1[2]; pa[0].u[3] = w1[3];
            pa[1].u[0] = w1[4]; pa[1].u[1] = w1[5]; pa[1].u[2] = w1[6]; pa[1].u[3] = w1[7];
            __builtin_amdgcn_s_setprio(1);
#pragma unroll
            for (int ks = 0; ks < 2; ks++) {
                bf16x8 v0 = *reinterpret_cast<const bf16x8*>(vbuf + offL[2 + ks]);
                bf16x8 v1 = *reinterpret_cast<const bf16x8*>(vbuf + offH[2 + ks]);
                lacc = MFMA32(pa[ks].v, onesf.v, lacc);
                oacc0 = MFMA32(pa[ks].v, v0, oacc0);
                oacc1 = MFMA32(pa[ks].v, v1, oacc1);
            }
            __builtin_amdgcn_s_setprio(0);
        }

        __syncthreads();  // drains stage (vmcnt) + all LDS reads before swap
    }

    // ---- normalize + write O (bf16): lacc rows match oacc rows exactly ----
#pragma unroll
    for (int reg = 0; reg < 16; reg++) {
        const int rr = (reg & 3) + 8 * (reg >> 2) + 4 * hi;
        const float ir = 1.0f / lacc[reg];
        const size_t rowoff = (size_t)(b * 2048 + q0 + rr) * 1024 + h * 64 + c;
        O[rowoff]      = f2bf_u(oacc0[reg] * ir);
        O[rowoff + 32] = f2bf_u(oacc1[reg] * ir);
    }
}

// ---------------------------------------------------------------------------
// Residual + LayerNorm v2: one row per WAVE (4 rows/block, grid 2048).
// 16 elems/lane in registers; pure shfl_xor reductions -- no LDS, no barriers.
// ---------------------------------------------------------------------------
__global__ __launch_bounds__(256) void resid_ln(const unsigned short* __restrict__ O,
                                                const float* __restrict__ Qin,
                                                const float* __restrict__ gamma,
                                                const float* __restrict__ beta,
                                                float* __restrict__ out) {
    const int wave = threadIdx.x >> 6, lane = threadIdx.x & 63;
    const int row = blockIdx.x * 4 + wave;
    const size_t base = (size_t)row * 1024 + lane * 16;
    const int col = lane * 16;

    float x[16];
#pragma unroll
    for (int v = 0; v < 2; v++) {
        const ushort8v o8 = *reinterpret_cast<const ushort8v*>(O + base + v * 8);
        const float4 qa = *reinterpret_cast<const float4*>(Qin + base + v * 8);
        const float4 qb = *reinterpret_cast<const float4*>(Qin + base + v * 8 + 4);
        x[v * 8 + 0] = bf2f(o8[0]) + qa.x;
        x[v * 8 + 1] = bf2f(o8[1]) + qa.y;
        x[v * 8 + 2] = bf2f(o8[2]) + qa.z;
        x[v * 8 + 3] = bf2f(o8[3]) + qa.w;
        x[v * 8 + 4] = bf2f(o8[4]) + qb.x;
        x[v * 8 + 5] = bf2f(o8[5]) + qb.y;
        x[v * 8 + 6] = bf2f(o8[6]) + qb.z;
        x[v * 8 + 7] = bf2f(o8[7]) + qb.w;
    }

    float s = 0.0f;
#pragma unroll
    for (int j = 0; j < 16; j++) s += x[j];
#pragma unroll
    for (int off = 32; off >= 1; off >>= 1) s += __shfl_xor(s, off, 64);
    const float mean = s * (1.0f / 1024.0f);

    float vs = 0.0f;
#pragma unroll
    for (int j = 0; j < 16; j++) {
        x[j] -= mean;
        vs += x[j] * x[j];
    }
#pragma unroll
    for (int off = 32; off >= 1; off >>= 1) vs += __shfl_xor(vs, off, 64);
    const float rstd = rsqrtf(vs * (1.0f / 1024.0f) + 1e-5f);

#pragma unroll
    for (int v = 0; v < 4; v++) {
        const float4 g = *reinterpret_cast<const float4*>(gamma + col + v * 4);
        const float4 be = *reinterpret_cast<const float4*>(beta + col + v * 4);
        float4 r;
        r.x = x[v * 4 + 0] * rstd * g.x + be.x;
        r.y = x[v * 4 + 1] * rstd * g.y + be.y;
        r.z = x[v * 4 + 2] * rstd * g.z + be.z;
        r.w = x[v * 4 + 3] * rstd * g.w + be.w;
        *reinterpret_cast<float4*>(out + base + v * 4) = r;
    }
}

// ---------------------------------------------------------------------------
extern "C" void kernel_launch(void* const* d_in, const int* in_sizes, int n_in,
                              void* d_out, int out_size, void* d_ws, size_t ws_size,
                              hipStream_t stream) {
    const float* q_in = (const float*)d_in[0];
    const float* k_in = (const float*)d_in[1];
    const float* v_in = (const float*)d_in[2];
    const int* mask = (const int*)d_in[3];
    const float* Wq = (const float*)d_in[4];
    const float* bq = (const float*)d_in[5];
    const float* Wk = (const float*)d_in[6];
    const float* bk = (const float*)d_in[7];
    const float* Wv = (const float*)d_in[8];
    const float* bv = (const float*)d_in[9];
    const float* gamma = (const float*)d_in[10];
    const float* beta = (const float*)d_in[11];
    float* out = (float*)d_out;

    unsigned short* wtq = (unsigned short*)d_ws;         // 3 x 1M bf16
    unsigned short* wtk = wtq + 1024 * 1024;
    unsigned short* wtv = wtk + 1024 * 1024;
    unsigned short* Qb = wtv + 1024 * 1024;              // 3 x 8M bf16
    unsigned short* Kb = Qb + 8192 * 1024;
    unsigned short* Vtb = Kb + 8192 * 1024;
    unsigned short* Obuf = Vtb + 8192 * 1024;            // 8M bf16

    dim3 tb(256);
    wt_cast<<<dim3(16, 16, 3), tb, 0, stream>>>(Wq, Wk, Wv, wtq, wtk, wtv);
    qkv_gemm4<<<dim3(1536), tb, 0, stream>>>(q_in, k_in, v_in, wtq, wtk, wtv,
                                             bq, bk, bv, mask, Qb, Kb, Vtb);
    flash_attn<<<dim3(1024), tb, 0, stream>>>(Qb, Kb, Vtb, Obuf);
    resid_ln<<<dim3(2048), tb, 0, stream>>>(Obuf, q_in, gamma, beta, out);
}

// Round 15
// 179.050 us; speedup vs baseline: 1.0238x; 1.0238x over previous
//
#include <hip/hip_runtime.h>
#include <hip/hip_bf16.h>
#include <stdint.h>

typedef __bf16 bf16x8 __attribute__((ext_vector_type(8)));
typedef float f32x4 __attribute__((ext_vector_type(4)));
typedef float f32x16 __attribute__((ext_vector_type(16)));
typedef unsigned short ushort8v __attribute__((ext_vector_type(8)));
typedef unsigned short ushort4v __attribute__((ext_vector_type(4)));
typedef uint32_t uint2v __attribute__((ext_vector_type(2)));
typedef uint32_t uint4v __attribute__((ext_vector_type(4)));

#define MFMA16(a, b, c) __builtin_amdgcn_mfma_f32_16x16x32_bf16(a, b, c, 0, 0, 0)
#define MFMA32(a, b, c) __builtin_amdgcn_mfma_f32_32x32x16_bf16(a, b, c, 0, 0, 0)

// async global->LDS, 16B per lane; LDS dest = wave-uniform base + lane*16
#define GLOAD_LDS16(g, l)                                                        \
    __builtin_amdgcn_global_load_lds(                                            \
        (const __attribute__((address_space(1))) uint32_t*)(g),                  \
        (__attribute__((address_space(3))) uint32_t*)(l), 16, 0, 0)

#define QSCALE 0.1803368801f  // 0.125 * log2(e)

__device__ __forceinline__ unsigned short f2bf_u(float f) {
    union { float f; uint32_t u; } cv; cv.f = f;
    uint32_t u = cv.u;
    uint32_t r = (u + 0x7FFFu + ((u >> 16) & 1u)) >> 16;
    return (unsigned short)r;
}

__device__ __forceinline__ float bf2f(unsigned short u) {
    union { uint32_t u; float f; } cv;
    cv.u = (uint32_t)u << 16;
    return cv.f;
}

__device__ __forceinline__ uint32_t pkbf(float a, float b) {
    union { __hip_bfloat162 h; uint32_t u; } cv;
    cv.h = __float22bfloat162_rn(make_float2(a, b));
    return cv.u;
}

__device__ __forceinline__ float fexp2(float x) { return __builtin_amdgcn_exp2f(x); }

// ---------------------------------------------------------------------------
// Transpose + cast: Wt[n][k] = bf16(W[k][n]); z selects Wq/Wk/Wv.
// ---------------------------------------------------------------------------
__global__ __launch_bounds__(256) void wt_cast(const float* __restrict__ W0,
                                               const float* __restrict__ W1,
                                               const float* __restrict__ W2,
                                               unsigned short* __restrict__ T0,
                                               unsigned short* __restrict__ T1,
                                               unsigned short* __restrict__ T2) {
    const int z = blockIdx.z;
    const float* W = z == 0 ? W0 : (z == 1 ? W1 : W2);
    unsigned short* Wt = z == 0 ? T0 : (z == 1 ? T1 : T2);
    __shared__ float t[32][33];
    const int tx = threadIdx.x & 31, ty = threadIdx.x >> 5;  // 32 x 8
    const int n0 = blockIdx.x * 32, k0 = blockIdx.y * 32;
#pragma unroll
    for (int i = 0; i < 4; i++) {
        int r = i * 8 + ty;
        t[r][tx] = W[(size_t)(k0 + r) * 1024 + n0 + tx];
    }
    __syncthreads();
#pragma unroll
    for (int i = 0; i < 4; i++) {
        int r = i * 8 + ty;
        Wt[(size_t)(n0 + r) * 1024 + k0 + tx] = f2bf_u(t[tx][r]);
    }
}

// ---------------------------------------------------------------------------
// QKV GEMM v4: out = relu(A_fp32 @ W + bias), A converted to bf16 in-kernel.
// W staged via global_load_lds (DMA); A reg-staged with the load/write SPLIT
// across K-iterations: LOAD_A(col k+2) issued at iter k, consumed by WRITE_A
// at iter k+1 after a full MFMA+barrier of slack. BK=32 double-buffered,
// one barrier per K-step. 1-D grid 1536, XCD remap: XCD x owns m-panels
// [8x,8x+8). z==0 (Q): epilogue folds attention scale + query mask.
// z==2 (V): writes transposed [B,H,dh,S].
// ---------------------------------------------------------------------------
__global__ __launch_bounds__(256) void qkv_gemm4(
    const float* __restrict__ Aq, const float* __restrict__ Ak,
    const float* __restrict__ Av,
    const unsigned short* __restrict__ Wq, const unsigned short* __restrict__ Wk,
    const unsigned short* __restrict__ Wv,
    const float* __restrict__ biasq, const float* __restrict__ biask,
    const float* __restrict__ biasv, const int* __restrict__ mask,
    unsigned short* __restrict__ outq, unsigned short* __restrict__ outk,
    unsigned short* __restrict__ outv) {
    __shared__ __align__(16) unsigned short aS[2][128 * 32];
    __shared__ __align__(16) unsigned short wS[2][128 * 32];
    const int id = blockIdx.x;          // 0..1535
    const int xcd = id & 7;
    const int local = id >> 3;          // 0..191
    const int z = local >> 6;           // 0..2
    const int l2i = local & 63;         // 0..63
    const int m0 = (xcd * 8 + (l2i >> 3)) * 128;
    const int n0 = (l2i & 7) * 128;

    const float* A = z == 0 ? Aq : (z == 1 ? Ak : Av);
    const unsigned short* Wt = z == 0 ? Wq : (z == 1 ? Wk : Wv);
    const float* bias = z == 0 ? biasq : (z == 1 ? biask : biasv);
    unsigned short* out = z == 0 ? outq : (z == 1 ? outk : outv);
    const bool vt = (z == 2);

    const int tid = threadIdx.x;
    const int lane = tid & 63, wave = tid >> 6;
    const int rrow = lane & 15, rgrp = lane >> 4;
    const int wm = wave >> 1, wn = wave & 1;

    const int row0 = tid >> 2, c0 = tid & 3;
    const int row1 = (tid + 256) >> 2;
    const int arow_f = wm * 64 + rrow;                   // + mi*16
    const int brow_f = wn * 64 + rrow;                   // + ni*16

    f32x4 acc[4][4];
#pragma unroll
    for (int i = 0; i < 4; i++)
#pragma unroll
        for (int j = 0; j < 4; j++) acc[i][j] = (f32x4)0.0f;

    auto STAGE_W = [&](int k0, int bufi) {
        char* dst = (char*)&wS[bufi][0] + wave * 1024;   // + implicit lane*16
        GLOAD_LDS16((const char*)Wt + ((size_t)(n0 + row0) * 1024 + k0 + c0 * 8) * 2, dst);
        GLOAD_LDS16((const char*)Wt + ((size_t)(n0 + row1) * 1024 + k0 + c0 * 8) * 2,
                    dst + 4096);
    };
    auto LOAD_A = [&](int k0, float4* r) {
#pragma unroll
        for (int i = 0; i < 4; i++) {
            const int g = i * 256 + tid, row = g >> 3, qc = g & 7;
            r[i] = *reinterpret_cast<const float4*>(A + (size_t)(m0 + row) * 1024 + k0 + qc * 4);
        }
    };
    auto WRITE_A = [&](const float4* r, int bufi) {
#pragma unroll
        for (int i = 0; i < 4; i++) {
            const int g = i * 256 + tid, row = g >> 3, qc = g & 7;
            uint2v w;
            w[0] = pkbf(r[i].x, r[i].y);
            w[1] = pkbf(r[i].z, r[i].w);
            *reinterpret_cast<uint2v*>((char*)&aS[bufi][0] + row * 64 + qc * 8) = w;
        }
    };

    float4 aload[4];
    // prologue: col 0 -> buf0 (one-time vmcnt(0)); issue col 1 for iter 0.
    LOAD_A(0, aload);
    STAGE_W(0, 0);
    WRITE_A(aload, 0);
    LOAD_A(32, aload);
    __syncthreads();

    for (int ks = 0; ks < 32; ks++) {
        const int cur = ks & 1;
        if (ks < 31) {
            WRITE_A(aload, cur ^ 1);            // data for col ks+1 (loaded iter ks-1)
            STAGE_W((ks + 1) * 32, cur ^ 1);
            if (ks < 30) LOAD_A((ks + 2) * 32, aload);
        }

        bf16x8 af[4], bfr[4];
#pragma unroll
        for (int mi = 0; mi < 4; mi++)
            af[mi] = *reinterpret_cast<const bf16x8*>(
                (const char*)&aS[cur][0] + (arow_f + mi * 16) * 64 + rgrp * 16);
#pragma unroll
        for (int ni = 0; ni < 4; ni++)
            bfr[ni] = *reinterpret_cast<const bf16x8*>(
                (const char*)&wS[cur][0] + (brow_f + ni * 16) * 64 + rgrp * 16);
        __builtin_amdgcn_s_setprio(1);
#pragma unroll
        for (int mi = 0; mi < 4; mi++)
#pragma unroll
            for (int ni = 0; ni < 4; ni++)
                acc[mi][ni] = MFMA16(af[mi], bfr[ni], acc[mi][ni]);
        __builtin_amdgcn_s_setprio(0);

        __syncthreads();
    }

    // Epilogue: bias + relu (+ Q scale*mask) + bf16, scatter head-split.
#pragma unroll
    for (int mi = 0; mi < 4; mi++) {
        const int mbase = m0 + wm * 64 + mi * 16 + rgrp * 4;
        const int b = mbase >> 11, s = mbase & 2047;
        float qs[4];
#pragma unroll
        for (int jr = 0; jr < 4; jr++)
            qs[jr] = (z != 0) ? 1.0f : (mask[b * 2048 + s + jr] ? QSCALE : 0.0f);
#pragma unroll
        for (int ni = 0; ni < 4; ni++) {
            const int n = n0 + wn * 64 + ni * 16 + rrow;
            const float bv = bias[n];
            const int h = n >> 6, d = n & 63;
            if (vt) {
                ushort4v pv;
#pragma unroll
                for (int jr = 0; jr < 4; jr++)
                    pv[jr] = f2bf_u(fmaxf(acc[mi][ni][jr] + bv, 0.0f));
                *reinterpret_cast<ushort4v*>(out + ((size_t)((b * 16 + h) * 64 + d)) * 2048 + s) = pv;
            } else {
#pragma unroll
                for (int jr = 0; jr < 4; jr++)
                    out[((size_t)((b * 16 + h) * 2048 + (s + jr))) * 64 + d] =
                        f2bf_u(fmaxf(acc[mi][ni][jr] + bv, 0.0f) * qs[jr]);
            }
        }
    }
}

// ---------------------------------------------------------------------------
// Flash attention. 4 waves/block share one (b,h); K/V tiles staged to LDS via
// global_load_lds (double-buffered 2-phase). Swapped-QK^T 32x32. Q pre-scaled
// by mask*0.125*log2e, so P = 2^S with fixed m=0 (scores bounded); masked
// rows Q=0 -> P=1 uniform (= reference). P->A-fragment pack via
// v_permlane32_swap_b32. l via MFMA (P . ones); O written bf16.
// ---------------------------------------------------------------------------
__global__ __launch_bounds__(256, 4) void flash_attn(const unsigned short* __restrict__ Qg,
                                                     const unsigned short* __restrict__ Kg,
                                                     const unsigned short* __restrict__ Vt,
                                                     unsigned short* __restrict__ O) {
    __shared__ __align__(16) unsigned short ldsK[2][64 * 64];  // 8KB per buffer
    __shared__ __align__(16) unsigned short ldsV[2][64 * 64];
    const int tid = threadIdx.x;
    const int lane = tid & 63, wave = tid >> 6;
    const int c = lane & 31, hi = lane >> 5;
    const int bid = blockIdx.x;                      // 1024 blocks
    const int swzb = (bid & 7) * 128 + (bid >> 3);   // XCD-contiguous block id
    const int gid = swzb * 4 + wave;                 // wave id in [0,4096)
    const int bh = gid >> 6;                         // all 4 waves: same bh
    const int q0 = (gid & 63) * 32;
    const int b = bh >> 4, h = bh & 15;
    const size_t base = (size_t)bh * (2048 * 64);
    const unsigned short* Qb = Qg + base;
    const unsigned short* Kb = Kg + base;
    const unsigned short* Vb = Vt + base;  // [64][2048]

    // staging constants: lane covers 16B chunk (lane&7) of row stripe (lane>>3)
    const int srow = lane >> 3;                 // 0..7
    const int schunk = (lane & 7) ^ srow;       // inverse-swizzled source chunk
    int offL[4], offH[4];
#pragma unroll
    for (int ds = 0; ds < 4; ds++) {
        offL[ds] = c * 128 + ((((ds << 1) + hi) ^ (c & 7)) << 4);
        offH[ds] = offL[ds] + 32 * 128;
    }

    bf16x8 qf[4];
#pragma unroll
    for (int ds = 0; ds < 4; ds++)
        qf[ds] = *reinterpret_cast<const bf16x8*>(Qb + (size_t)(q0 + c) * 64 + ds * 16 + hi * 8);

    union { uint32_t u[4]; bf16x8 v; } onesf;
#pragma unroll
    for (int i = 0; i < 4; i++) onesf.u[i] = 0x3F803F80u;  // bf16 1.0 x8

    f32x16 lacc = (f32x16)0.0f;
    f32x16 oacc0 = (f32x16)0.0f, oacc1 = (f32x16)0.0f;

    auto STAGE = [&](int kt, int bufi) {
        const char* ktile = (const char*)Kb + (size_t)kt * 8192;      // contiguous
        const char* vtile = (const char*)Vb + (size_t)kt * 128;       // strided rows
        char* kdst = (char*)&ldsK[bufi][0] + wave * 2048;
        char* vdst = (char*)&ldsV[bufi][0] + wave * 2048;
#pragma unroll
        for (int i = 0; i < 2; i++) {
            const int row = wave * 16 + i * 8 + srow;
            GLOAD_LDS16(ktile + row * 128 + schunk * 16, kdst + i * 1024);
            GLOAD_LDS16(vtile + (size_t)row * 4096 + schunk * 16, vdst + i * 1024);
        }
    };

    STAGE(0, 0);
    __syncthreads();

    for (int kt = 0; kt < 32; kt++) {
        const int cur = kt & 1;
        if (kt < 31) STAGE(kt + 1, cur ^ 1);
        const char* kbuf = (const char*)&ldsK[cur][0];
        const char* vbuf = (const char*)&ldsV[cur][0];

        // ---- S^T = K Q^T (Q pre-scaled; base-2 domain) ----
        f32x16 sacc0 = (f32x16)0.0f, sacc1 = (f32x16)0.0f;
        __builtin_amdgcn_s_setprio(1);
#pragma unroll
        for (int ds = 0; ds < 4; ds++) {
            bf16x8 k0 = *reinterpret_cast<const bf16x8*>(kbuf + offL[ds]);
            bf16x8 k1 = *reinterpret_cast<const bf16x8*>(kbuf + offH[ds]);
            sacc0 = MFMA32(k0, qf[ds], sacc0);
            sacc1 = MFMA32(k1, qf[ds], sacc1);
        }
        __builtin_amdgcn_s_setprio(0);

        // ---- P = 2^S in place ----
#pragma unroll
        for (int j = 0; j < 16; j++) {
            sacc0[j] = fexp2(sacc0[j]);
            sacc1[j] = fexp2(sacc1[j]);
        }

        // ---- half 0: pack P(keys 0..31) via permlane32_swap, l, O += P V ----
        {
            uint32_t w0[8];
#pragma unroll
            for (int i = 0; i < 8; i++) w0[i] = pkbf(sacc0[2 * i], sacc0[2 * i + 1]);
            asm("v_permlane32_swap_b32 %0, %1" : "+v"(w0[0]), "+v"(w0[2]));
            asm("v_permlane32_swap_b32 %0, %1" : "+v"(w0[1]), "+v"(w0[3]));
            asm("v_permlane32_swap_b32 %0, %1" : "+v"(w0[4]), "+v"(w0[6]));
            asm("v_permlane32_swap_b32 %0, %1" : "+v"(w0[5]), "+v"(w0[7]));
            union { uint32_t u[4]; bf16x8 v; } pa[2];
            pa[0].u[0] = w0[0]; pa[0].u[1] = w0[1]; pa[0].u[2] = w0[2]; pa[0].u[3] = w0[3];
            pa[1].u[0] = w0[4]; pa[1].u[1] = w0[5]; pa[1].u[2] = w0[6]; pa[1].u[3] = w0[7];
            __builtin_amdgcn_s_setprio(1);
#pragma unroll
            for (int ks = 0; ks < 2; ks++) {
                bf16x8 v0 = *reinterpret_cast<const bf16x8*>(vbuf + offL[ks]);
                bf16x8 v1 = *reinterpret_cast<const bf16x8*>(vbuf + offH[ks]);
                lacc = MFMA32(pa[ks].v, onesf.v, lacc);
                oacc0 = MFMA32(pa[ks].v, v0, oacc0);
                oacc1 = MFMA32(pa[ks].v, v1, oacc1);
            }
            __builtin_amdgcn_s_setprio(0);
        }
        // ---- half 1: keys 32..63 ----
        {
            uint32_t w1[8];
#pragma unroll
            for (int i = 0; i < 8; i++) w1[i] = pkbf(sacc1[2 * i], sacc1[2 * i + 1]);
            asm("v_permlane32_swap_b32 %0, %1" : "+v"(w1[0]), "+v"(w1[2]));
            asm("v_permlane32_swap_b32 %0, %1" : "+v"(w1[1]), "+v"(w1[3]));
            asm("v_permlane32_swap_b32 %0, %1" : "+v"(w1[4]), "+v"(w1[6]));
            asm("v_permlane32_swap_b32 %0, %1" : "+v"(w1[5]), "+v"(w1[7]));
            union { uint32_t u[4]; bf16x8 v; } pa[2];
            pa[0].u[0] = w1[0]; pa[0].u[1] = w1[1]; pa[0].u[2] = w1[2]; pa[0].u[3] = w1[3];
            pa[1].u[0] = w1[4]; pa[1].u[1] = w1[5]; pa[1].u[2] = w1[6]; pa[1].u[3] = w1[7];
            __builtin_amdgcn_s_setprio(1);
#pragma unroll
            for (int ks = 0; ks < 2; ks++) {
                bf16x8 v0 = *reinterpret_cast<const bf16x8*>(vbuf + offL[2 + ks]);
                bf16x8 v1 = *reinterpret_cast<const bf16x8*>(vbuf + offH[2 + ks]);
                lacc = MFMA32(pa[ks].v, onesf.v, lacc);
                oacc0 = MFMA32(pa[ks].v, v0, oacc0);
                oacc1 = MFMA32(pa[ks].v, v1, oacc1);
            }
            __builtin_amdgcn_s_setprio(0);
        }

        __syncthreads();  // drains stage (vmcnt) + all LDS reads before swap
    }

    // ---- normalize + write O (bf16): lacc rows match oacc rows exactly ----
#pragma unroll
    for (int reg = 0; reg < 16; reg++) {
        const int rr = (reg & 3) + 8 * (reg >> 2) + 4 * hi;
        const float ir = 1.0f / lacc[reg];
        const size_t rowoff = (size_t)(b * 2048 + q0 + rr) * 1024 + h * 64 + c;
        O[rowoff]      = f2bf_u(oacc0[reg] * ir);
        O[rowoff + 32] = f2bf_u(oacc1[reg] * ir);
    }
}

// ---------------------------------------------------------------------------
// Residual + LayerNorm: out = LN(O_bf16 + queries_fp32) * gamma + beta.
// ---------------------------------------------------------------------------
__global__ __launch_bounds__(256) void resid_ln(const unsigned short* __restrict__ O,
                                                const float* __restrict__ Qin,
                                                const float* __restrict__ gamma,
                                                const float* __restrict__ beta,
                                                float* __restrict__ out) {
    __shared__ float red[4];
    const int row = blockIdx.x, tid = threadIdx.x;
    const size_t base = (size_t)row * 1024 + tid * 4;
    const ushort4v o4 = *reinterpret_cast<const ushort4v*>(O + base);
    const float4 q4 = *reinterpret_cast<const float4*>(Qin + base);
    float x0 = bf2f(o4[0]) + q4.x, x1 = bf2f(o4[1]) + q4.y;
    float x2 = bf2f(o4[2]) + q4.z, x3 = bf2f(o4[3]) + q4.w;

    float s = x0 + x1 + x2 + x3;
#pragma unroll
    for (int off = 32; off >= 1; off >>= 1) s += __shfl_xor(s, off, 64);
    const int w = tid >> 6;
    if ((tid & 63) == 0) red[w] = s;
    __syncthreads();
    const float mean = (red[0] + red[1] + red[2] + red[3]) * (1.0f / 1024.0f);
    __syncthreads();

    const float d0 = x0 - mean, d1 = x1 - mean, d2 = x2 - mean, d3 = x3 - mean;
    float vs = d0 * d0 + d1 * d1 + d2 * d2 + d3 * d3;
#pragma unroll
    for (int off = 32; off >= 1; off >>= 1) vs += __shfl_xor(vs, off, 64);
    if ((tid & 63) == 0) red[w] = vs;
    __syncthreads();
    const float var = (red[0] + red[1] + red[2] + red[3]) * (1.0f / 1024.0f);
    const float rstd = rsqrtf(var + 1e-5f);

    float4 g = *reinterpret_cast<const float4*>(gamma + tid * 4);
    float4 be = *reinterpret_cast<const float4*>(beta + tid * 4);
    float4 r;
    r.x = d0 * rstd * g.x + be.x;
    r.y = d1 * rstd * g.y + be.y;
    r.z = d2 * rstd * g.z + be.z;
    r.w = d3 * rstd * g.w + be.w;
    *reinterpret_cast<float4*>(out + base) = r;
}

// ---------------------------------------------------------------------------
extern "C" void kernel_launch(void* const* d_in, const int* in_sizes, int n_in,
                              void* d_out, int out_size, void* d_ws, size_t ws_size,
                              hipStream_t stream) {
    const float* q_in = (const float*)d_in[0];
    const float* k_in = (const float*)d_in[1];
    const float* v_in = (const float*)d_in[2];
    const int* mask = (const int*)d_in[3];
    const float* Wq = (const float*)d_in[4];
    const float* bq = (const float*)d_in[5];
    const float* Wk = (const float*)d_in[6];
    const float* bk = (const float*)d_in[7];
    const float* Wv = (const float*)d_in[8];
    const float* bv = (const float*)d_in[9];
    const float* gamma = (const float*)d_in[10];
    const float* beta = (const float*)d_in[11];
    float* out = (float*)d_out;

    unsigned short* wtq = (unsigned short*)d_ws;         // 3 x 1M bf16
    unsigned short* wtk = wtq + 1024 * 1024;
    unsigned short* wtv = wtk + 1024 * 1024;
    unsigned short* Qb = wtv + 1024 * 1024;              // 3 x 8M bf16
    unsigned short* Kb = Qb + 8192 * 1024;
    unsigned short* Vtb = Kb + 8192 * 1024;
    unsigned short* Obuf = Vtb + 8192 * 1024;            // 8M bf16

    dim3 tb(256);
    wt_cast<<<dim3(32, 32, 3), tb, 0, stream>>>(Wq, Wk, Wv, wtq, wtk, wtv);
    qkv_gemm4<<<dim3(1536), tb, 0, stream>>>(q_in, k_in, v_in, wtq, wtk, wtv,
                                             bq, bk, bv, mask, Qb, Kb, Vtb);
    flash_attn<<<dim3(1024), tb, 0, stream>>>(Qb, Kb, Vtb, Obuf);
    resid_ln<<<dim3(8192), tb, 0, stream>>>(Obuf, q_in, gamma, beta, out);
}